// Round 2
// baseline (266.312 us; speedup 1.0000x reference)
//
#include <hip/hip_runtime.h>
#include <stdint.h>

// ---------------- problem constants ----------------
#define K_TOTAL   98304u     // 32 * 512 * 6
#define EMA_RATE  0.003f

// ---------------- select config ----------------
#define SBINS      16384     // sample histogram bins (top 14 bits of key)
#define SBIN_SHIFT 18
#define SAMPLE_VEC 131072    // float4s sampled = 524288 floats (1/48 of data)
#define STARGET    8192u     // sample count above threshold (~4x K when scaled)
#define P2_BINS    4096      // candidate histogram bins
#define P2_SHIFT   12        // bin width = 4096 keys
#define LCAP       1024      // per-block LDS candidate staging
#define CAP2       65536u    // final-bin candidate cap
#define EQCAP      256       // tie buffer

// monotone float->uint key: order(key) == order(float)
__device__ __forceinline__ unsigned f2key(float x) {
    unsigned u = __float_as_uint(x);
    return (u & 0x80000000u) ? ~u : (u | 0x80000000u);
}
__device__ __forceinline__ float key2f(unsigned key) {
    unsigned u = (key & 0x80000000u) ? (key & 0x7FFFFFFFu) : ~key;
    return __uint_as_float(u);
}

// ---------------- S1: sample histogram (first 2 MB, iid data) ----------------
__global__ __launch_bounds__(256) void sample_hist_kernel(
        const float4* __restrict__ in, unsigned* __restrict__ shist) {
    __shared__ unsigned h[SBINS];
    for (int i = threadIdx.x; i < SBINS; i += 256) h[i] = 0;
    __syncthreads();
    int stride = gridDim.x * 256;
    for (int i = blockIdx.x * 256 + threadIdx.x; i < SAMPLE_VEC; i += stride) {
        float4 v = in[i];
        atomicAdd(&h[f2key(v.x) >> SBIN_SHIFT], 1u);
        atomicAdd(&h[f2key(v.y) >> SBIN_SHIFT], 1u);
        atomicAdd(&h[f2key(v.z) >> SBIN_SHIFT], 1u);
        atomicAdd(&h[f2key(v.w) >> SBIN_SHIFT], 1u);
    }
    __syncthreads();
    for (int i = threadIdx.x; i < SBINS; i += 256) {
        unsigned c = h[i];
        if (c) atomicAdd(&shist[i], c);
    }
}

// ---------------- S2: pick conservative base key ----------------
__global__ __launch_bounds__(256) void sample_scan_kernel(
        const unsigned* __restrict__ shist, unsigned* __restrict__ res) {
    __shared__ unsigned psum[256];
    const int GB = SBINS / 256;               // 64 bins/thread, descending
    int t = threadIdx.x;
    int hi = SBINS - 1 - t * GB;
    unsigned s = 0;
    for (int j = 0; j < GB; ++j) s += shist[hi - j];
    psum[t] = s;
    __syncthreads();
    for (int off = 1; off < 256; off <<= 1) {
        unsigned o = (t >= off) ? psum[t - off] : 0u;
        __syncthreads();
        psum[t] += o;
        __syncthreads();
    }
    unsigned cum = psum[t] - s;               // samples strictly above my group
    for (int j = 0; j < GB; ++j) {
        unsigned c = shist[hi - j];
        if (cum < STARGET && cum + c >= STARGET) {
            unsigned bin = (unsigned)(hi - j);
            unsigned bb = (bin > 0) ? bin - 1 : 0;   // one extra margin bin
            res[0] = bb << SBIN_SHIFT;               // base key
        }
        cum += c;
    }
}

// ---------------- P2: single full-data pass — compact + 4096-bin hist -------
__global__ __launch_bounds__(256) void main_pass_kernel(
        const float4* __restrict__ in, const unsigned* __restrict__ res,
        float* __restrict__ cval, unsigned* __restrict__ cidx,
        unsigned* __restrict__ gcnt, unsigned* __restrict__ ghist,
        unsigned cap, int nvec) {
    __shared__ unsigned h[P2_BINS];
    __shared__ float    lval[LCAP];
    __shared__ unsigned lidx[LCAP];
    __shared__ unsigned lcnt, lbase;
    for (int i = threadIdx.x; i < P2_BINS; i += 256) h[i] = 0;
    if (threadIdx.x == 0) lcnt = 0;
    __syncthreads();
    unsigned base = res[0];
    int stride = gridDim.x * 256;
    for (int i = blockIdx.x * 256 + threadIdx.x; i < nvec; i += stride) {
        float4 v = in[i];
        unsigned idx = 4u * (unsigned)i;
        #pragma unroll
        for (int c = 0; c < 4; ++c) {
            float x = (c == 0) ? v.x : (c == 1) ? v.y : (c == 2) ? v.z : v.w;
            unsigned key = f2key(x);
            if (key >= base) {
                unsigned g = (key - base) >> P2_SHIFT;
                if (g > P2_BINS - 1) g = P2_BINS - 1;
                atomicAdd(&h[g], 1u);
                unsigned p = atomicAdd(&lcnt, 1u);
                if (p < LCAP) { lval[p] = x; lidx[p] = idx + c; }
                else {                          // LDS overflow fallback
                    unsigned q = atomicAdd(gcnt, 1u);
                    if (q < cap) { cval[q] = x; cidx[q] = idx + c; }
                }
            }
        }
    }
    __syncthreads();
    unsigned n = min(lcnt, (unsigned)LCAP);
    if (threadIdx.x == 0) lbase = atomicAdd(gcnt, n);
    __syncthreads();
    for (unsigned j = threadIdx.x; j < n; j += 256) {
        unsigned p = lbase + j;
        if (p < cap) { cval[p] = lval[j]; cidx[p] = lidx[j]; }
    }
    for (int i = threadIdx.x; i < P2_BINS; i += 256) {
        unsigned c = h[i];
        if (c) atomicAdd(&ghist[i], c);
    }
}

// ---------------- C2: scan candidate hist -> bin g*, need2 ----------------
__global__ __launch_bounds__(256) void find_g_kernel(
        const unsigned* __restrict__ ghist, unsigned* __restrict__ res2) {
    __shared__ unsigned psum[256];
    const int GB = P2_BINS / 256;             // 16 bins/thread, descending
    int t = threadIdx.x;
    int hi = P2_BINS - 1 - t * GB;
    unsigned s = 0;
    for (int j = 0; j < GB; ++j) s += ghist[hi - j];
    psum[t] = s;
    __syncthreads();
    for (int off = 1; off < 256; off <<= 1) {
        unsigned o = (t >= off) ? psum[t - off] : 0u;
        __syncthreads();
        psum[t] += o;
        __syncthreads();
    }
    unsigned cum = psum[t] - s;
    for (int j = 0; j < GB; ++j) {
        unsigned c = ghist[hi - j];
        if (cum < K_TOTAL && cum + c >= K_TOTAL) {
            res2[0] = (unsigned)(hi - j);     // g*
            res2[1] = K_TOTAL - cum;          // need2 inside bin g*
        }
        cum += c;
    }
}

// ---------------- C3: scatter definite winners, compact bin-g* -------------
__global__ __launch_bounds__(256) void scatter_kernel(
        const float* __restrict__ cval, const unsigned* __restrict__ cidx,
        const unsigned* __restrict__ gcnt, const unsigned* __restrict__ res,
        const unsigned* __restrict__ res2,
        float* __restrict__ cval2, unsigned* __restrict__ cidx2,
        unsigned* __restrict__ cnt2, unsigned cap,
        float* __restrict__ out) {
    unsigned nc = min(*gcnt, cap);
    unsigned base = res[0];
    unsigned gstar = res2[0];
    int stride = gridDim.x * 256;
    for (unsigned i = blockIdx.x * 256 + threadIdx.x; i < nc; i += stride) {
        float x = cval[i];
        unsigned key = f2key(x);
        unsigned g = (key - base) >> P2_SHIFT;
        if (g > P2_BINS - 1) g = P2_BINS - 1;
        if (g > gstar) {
            out[cidx[i]] = fmaxf(x, 0.0f);           // definite winner
        } else if (g == gstar) {
            unsigned p = atomicAdd(cnt2, 1u);
            if (p < CAP2) { cval2[p] = x; cidx2[p] = cidx[i]; }
        }
    }
}

// ---------------- C4: exact select in 4096-key range, ties, EMA ------------
__global__ __launch_bounds__(256) void final_kernel(
        const float* __restrict__ cval2, const unsigned* __restrict__ cidx2,
        const unsigned* __restrict__ cnt2,
        const unsigned* __restrict__ res, const unsigned* __restrict__ res2,
        float* __restrict__ out,
        const float* __restrict__ thr_in, float* __restrict__ thr_out) {
    __shared__ unsigned h[1 << P2_SHIFT];     // one bin per exact key
    __shared__ unsigned psum[256];
    __shared__ unsigned eqidx[EQCAP];
    __shared__ unsigned eqcnt;
    __shared__ unsigned sh_low, sh_need3;
    const int NB = 1 << P2_SHIFT;             // 4096
    int t = threadIdx.x;
    unsigned nc2   = min(*cnt2, CAP2);
    unsigned base3 = res[0] + (res2[0] << P2_SHIFT);
    unsigned need2 = res2[1];

    for (int i = t; i < NB; i += 256) h[i] = 0;
    if (t == 0) eqcnt = 0;
    __syncthreads();
    for (unsigned i = t; i < nc2; i += 256) {
        unsigned low = f2key(cval2[i]) - base3;
        if (low > (unsigned)(NB - 1)) low = NB - 1;
        atomicAdd(&h[low], 1u);
    }
    __syncthreads();

    const int GB = NB / 256;                  // 16 keys/thread, descending
    int hi = NB - 1 - t * GB;
    unsigned s = 0;
    for (int j = 0; j < GB; ++j) s += h[hi - j];
    psum[t] = s;
    __syncthreads();
    for (int off = 1; off < 256; off <<= 1) {
        unsigned o = (t >= off) ? psum[t - off] : 0u;
        __syncthreads();
        psum[t] += o;
        __syncthreads();
    }
    unsigned cum = psum[t] - s;
    for (int j = 0; j < GB; ++j) {
        unsigned c = h[hi - j];
        if (cum < need2 && cum + c >= need2) {
            sh_low = (unsigned)(hi - j);
            sh_need3 = need2 - cum;           // ties to accept at kth key
        }
        cum += c;
    }
    __syncthreads();
    unsigned kth_key = base3 + sh_low;
    unsigned need3   = sh_need3;

    for (unsigned i = t; i < nc2; i += 256) {
        float x = cval2[i];
        unsigned key = f2key(x);
        if (key > kth_key) {
            out[cidx2[i]] = fmaxf(x, 0.0f);
        } else if (key == kth_key) {
            unsigned p = atomicAdd(&eqcnt, 1u);
            if (p < EQCAP) eqidx[p] = cidx2[i];
        }
    }
    __syncthreads();

    // tie-break: lax.top_k picks lowest flat indices first
    unsigned ne = min(eqcnt, (unsigned)EQCAP);
    float vv = key2f(kth_key);
    for (unsigned e = t; e < ne; e += 256) {
        unsigned my = eqidx[e];
        unsigned rank = 0;
        for (unsigned f = 0; f < ne; ++f) rank += (eqidx[f] < my) ? 1u : 0u;
        if (rank < need3) out[my] = fmaxf(vv, 0.0f);
    }

    if (t == 0) {
        float mink = fmaxf(vv, 0.0f);         // relu(k-th largest)
        thr_out[0] = (1.0f - EMA_RATE) * thr_in[0] + EMA_RATE * mink;
    }
}

// ---------------- launch ----------------
extern "C" void kernel_launch(void* const* d_in, const int* in_sizes, int n_in,
                              void* d_out, int out_size, void* d_ws, size_t ws_size,
                              hipStream_t stream) {
    const float* feat   = (const float*)d_in[0];
    const float* thr_in = (const float*)d_in[1];
    float* out = (float*)d_out;
    int N    = in_sizes[0];      // 25165824
    int nvec = N / 4;

    // ---- workspace layout ----
    uint8_t* w = (uint8_t*)d_ws;
    unsigned* shist = (unsigned*)w;                        // 64 KB
    unsigned* ghist = (unsigned*)(w + (64 << 10));         // 16 KB
    unsigned* ctr   = (unsigned*)(w + (80 << 10));         // counters/res block
    unsigned* gcnt  = ctr + 0;
    unsigned* cnt2  = ctr + 1;
    unsigned* res   = ctr + 4;    // res[0] = base key
    unsigned* res2  = ctr + 8;    // res2[0] = g*, res2[1] = need2

    size_t cand_off = (size_t)1 << 20;
    size_t avail    = (ws_size > cand_off + (CAP2 * 8 + 4096))
                        ? (ws_size - cand_off - CAP2 * 8 - 4096) / 8 : 0;
    unsigned cap = (unsigned)((avail < (size_t)(4u << 20)) ? avail : (size_t)(4u << 20));
    float*    cval  = (float*)(w + cand_off);
    unsigned* cidx  = (unsigned*)(w + cand_off + (size_t)cap * 4);
    float*    cval2 = (float*)(w + cand_off + (size_t)cap * 8);
    unsigned* cidx2 = (unsigned*)(w + cand_off + (size_t)cap * 8 + CAP2 * 4);

    // zero hists + counters; zero the whole output (fill runs ~6.9 TB/s)
    hipMemsetAsync(d_ws, 0, (80 << 10) + 64, stream);
    hipMemsetAsync(d_out, 0, (size_t)N * 4, stream);

    sample_hist_kernel<<<128, 256, 0, stream>>>((const float4*)feat, shist);
    sample_scan_kernel<<<1,   256, 0, stream>>>(shist, res);
    main_pass_kernel  <<<1536, 256, 0, stream>>>((const float4*)feat, res,
                                                 cval, cidx, gcnt, ghist, cap, nvec);
    find_g_kernel     <<<1,   256, 0, stream>>>(ghist, res2);
    scatter_kernel    <<<64,  256, 0, stream>>>(cval, cidx, gcnt, res, res2,
                                                cval2, cidx2, cnt2, cap, out);
    final_kernel      <<<1,   256, 0, stream>>>(cval2, cidx2, cnt2, res, res2,
                                                out, thr_in, out + N);
}

// Round 3
// 238.371 us; speedup vs baseline: 1.1172x; 1.1172x over previous
//
#include <hip/hip_runtime.h>
#include <stdint.h>

// ---------------- problem constants ----------------
#define K_TOTAL   98304u     // 32 * 512 * 6
#define EMA_RATE  0.003f

// ---------------- select config ----------------
#define SBINS      16384     // sample histogram bins (top 14 bits of key)
#define SBIN_SHIFT 18
#define SAMPLE_VEC 131072    // float4s sampled = 524288 floats (1/48 of data)
#define STARGET    8192u     // sample count above threshold (~4x K when scaled)
#define P2_BINS    4096      // candidate histogram bins
#define P2_SHIFT   12        // bin width = 4096 keys
#define LCAP       1024      // per-block LDS candidate staging
#define CAP2       65536u    // final-bin candidate cap
#define EQCAP      256       // tie buffer

#define MP_BLOCKS  3072      // 3072*256*8 float4 = 6291456 = nvec exactly
#define MP_UNROLL  8

// monotone float->uint key: order(key) == order(float)
__device__ __forceinline__ unsigned f2key(float x) {
    unsigned u = __float_as_uint(x);
    return (u & 0x80000000u) ? ~u : (u | 0x80000000u);
}
__device__ __forceinline__ float key2f(unsigned key) {
    unsigned u = (key & 0x80000000u) ? (key & 0x7FFFFFFFu) : ~key;
    return __uint_as_float(u);
}

// ---------------- S1: sample histogram (first 2 MB, iid data) --------------
__global__ __launch_bounds__(256) void sample_hist_kernel(
        const float4* __restrict__ in, unsigned* __restrict__ shist) {
    __shared__ unsigned h[SBINS];
    for (int i = threadIdx.x; i < SBINS; i += 256) h[i] = 0;
    __syncthreads();
    // 128 blocks * 256 threads * 4 = 131072 float4 exactly; 4 batched loads
    unsigned tid = blockIdx.x * 256 + threadIdx.x;
    unsigned nth = gridDim.x * 256;
    float4 v[4];
    #pragma unroll
    for (int u = 0; u < 4; ++u) {
        unsigned j = tid + u * nth;
        v[u] = (j < SAMPLE_VEC) ? in[j] : make_float4(0.f, 0.f, 0.f, 0.f);
    }
    #pragma unroll
    for (int u = 0; u < 4; ++u) {
        unsigned j = tid + u * nth;
        if (j < SAMPLE_VEC) {
            atomicAdd(&h[f2key(v[u].x) >> SBIN_SHIFT], 1u);
            atomicAdd(&h[f2key(v[u].y) >> SBIN_SHIFT], 1u);
            atomicAdd(&h[f2key(v[u].z) >> SBIN_SHIFT], 1u);
            atomicAdd(&h[f2key(v[u].w) >> SBIN_SHIFT], 1u);
        }
    }
    __syncthreads();
    for (int i = threadIdx.x; i < SBINS; i += 256) {
        unsigned c = h[i];
        if (c) atomicAdd(&shist[i], c);
    }
}

// ---------------- S2: pick conservative base key ---------------------------
__global__ __launch_bounds__(1024) void sample_scan_kernel(
        const unsigned* __restrict__ shist, unsigned* __restrict__ res) {
    __shared__ unsigned psum[1024];
    const int T = 1024;
    const int GB = SBINS / T;                 // 16 bins/thread, descending
    int t = threadIdx.x;
    int hi = SBINS - 1 - t * GB;
    unsigned c[GB];
    #pragma unroll
    for (int j = 0; j < GB; ++j) c[j] = shist[hi - j];   // independent loads
    unsigned s = 0;
    #pragma unroll
    for (int j = 0; j < GB; ++j) s += c[j];
    psum[t] = s;
    __syncthreads();
    for (int off = 1; off < T; off <<= 1) {
        unsigned o = (t >= off) ? psum[t - off] : 0u;
        __syncthreads();
        psum[t] += o;
        __syncthreads();
    }
    unsigned cum = psum[t] - s;               // samples strictly above my group
    for (int j = 0; j < GB; ++j) {
        if (cum < STARGET && cum + c[j] >= STARGET) {
            unsigned bin = (unsigned)(hi - j);
            unsigned bb = (bin > 0) ? bin - 1 : 0;   // one extra margin bin
            res[0] = bb << SBIN_SHIFT;               // base key
        }
        cum += c[j];
    }
}

// ---------------- P2: single full-data pass — compact candidates -----------
__global__ __launch_bounds__(256) void main_pass_kernel(
        const float4* __restrict__ in, const unsigned* __restrict__ res,
        float* __restrict__ cval, unsigned* __restrict__ cidx,
        unsigned* __restrict__ gcnt, unsigned cap, int nvec) {
    __shared__ float    lval[LCAP];
    __shared__ unsigned lidx[LCAP];
    __shared__ unsigned lcnt, lbase;
    if (threadIdx.x == 0) lcnt = 0;
    __syncthreads();
    unsigned base = res[0];
    unsigned tid = blockIdx.x * 256 + threadIdx.x;
    unsigned nth = gridDim.x * 256;
    for (unsigned i0 = tid; i0 < (unsigned)nvec; i0 += MP_UNROLL * nth) {
        float4 v[MP_UNROLL];
        #pragma unroll
        for (int u = 0; u < MP_UNROLL; ++u) {     // 8 independent loads (MLP)
            unsigned j = i0 + u * nth;
            v[u] = (j < (unsigned)nvec) ? in[j]
                   : make_float4(-1e30f, -1e30f, -1e30f, -1e30f);
        }
        #pragma unroll
        for (int u = 0; u < MP_UNROLL; ++u) {
            unsigned j = i0 + u * nth;
            unsigned idx = 4u * j;
            float xs[4] = {v[u].x, v[u].y, v[u].z, v[u].w};
            #pragma unroll
            for (int c = 0; c < 4; ++c) {
                unsigned key = f2key(xs[c]);
                if (key >= base) {                // ~1.7% taken
                    unsigned p = atomicAdd(&lcnt, 1u);
                    if (p < LCAP) { lval[p] = xs[c]; lidx[p] = idx + c; }
                    else {                        // overflow fallback
                        unsigned q = atomicAdd(gcnt, 1u);
                        if (q < cap) { cval[q] = xs[c]; cidx[q] = idx + c; }
                    }
                }
            }
        }
    }
    __syncthreads();
    unsigned n = min(lcnt, (unsigned)LCAP);
    if (threadIdx.x == 0) lbase = atomicAdd(gcnt, n);
    __syncthreads();
    for (unsigned j = threadIdx.x; j < n; j += 256) {
        unsigned p = lbase + j;
        if (p < cap) { cval[p] = lval[j]; cidx[p] = lidx[j]; }
    }
}

// ---------------- CH: histogram the compacted candidates -------------------
__global__ __launch_bounds__(256) void cand_hist_kernel(
        const float* __restrict__ cval, const unsigned* __restrict__ gcnt,
        const unsigned* __restrict__ res, unsigned* __restrict__ ghist,
        unsigned cap) {
    __shared__ unsigned h[P2_BINS];
    for (int i = threadIdx.x; i < P2_BINS; i += 256) h[i] = 0;
    __syncthreads();
    unsigned nc = min(*gcnt, cap);
    unsigned base = res[0];
    unsigned tid = blockIdx.x * 256 + threadIdx.x;
    unsigned nth = gridDim.x * 256;
    for (unsigned i0 = tid; i0 < nc; i0 += 4 * nth) {
        float v[4];
        #pragma unroll
        for (int u = 0; u < 4; ++u) {
            unsigned j = i0 + u * nth;
            v[u] = (j < nc) ? cval[j] : -1e30f;
        }
        #pragma unroll
        for (int u = 0; u < 4; ++u) {
            unsigned j = i0 + u * nth;
            if (j < nc) {
                unsigned g = (f2key(v[u]) - base) >> P2_SHIFT;
                if (g > P2_BINS - 1) g = P2_BINS - 1;
                atomicAdd(&h[g], 1u);
            }
        }
    }
    __syncthreads();
    for (int i = threadIdx.x; i < P2_BINS; i += 256) {
        unsigned c = h[i];
        if (c) atomicAdd(&ghist[i], c);
    }
}

// ---------------- C2: scan candidate hist -> bin g*, need2 -----------------
__global__ __launch_bounds__(1024) void find_g_kernel(
        const unsigned* __restrict__ ghist, unsigned* __restrict__ res2) {
    __shared__ unsigned psum[1024];
    const int T = 1024;
    const int GB = P2_BINS / T;               // 4 bins/thread, descending
    int t = threadIdx.x;
    int hi = P2_BINS - 1 - t * GB;
    unsigned c[GB];
    #pragma unroll
    for (int j = 0; j < GB; ++j) c[j] = ghist[hi - j];
    unsigned s = 0;
    #pragma unroll
    for (int j = 0; j < GB; ++j) s += c[j];
    psum[t] = s;
    __syncthreads();
    for (int off = 1; off < T; off <<= 1) {
        unsigned o = (t >= off) ? psum[t - off] : 0u;
        __syncthreads();
        psum[t] += o;
        __syncthreads();
    }
    unsigned cum = psum[t] - s;
    for (int j = 0; j < GB; ++j) {
        if (cum < K_TOTAL && cum + c[j] >= K_TOTAL) {
            res2[0] = (unsigned)(hi - j);     // g*
            res2[1] = K_TOTAL - cum;          // need2 inside bin g*
        }
        cum += c[j];
    }
}

// ---------------- C3: scatter definite winners, compact bin-g* -------------
__global__ __launch_bounds__(256) void scatter_kernel(
        const float* __restrict__ cval, const unsigned* __restrict__ cidx,
        const unsigned* __restrict__ gcnt, const unsigned* __restrict__ res,
        const unsigned* __restrict__ res2,
        float* __restrict__ cval2, unsigned* __restrict__ cidx2,
        unsigned* __restrict__ cnt2, unsigned cap,
        float* __restrict__ out) {
    unsigned nc = min(*gcnt, cap);
    unsigned base = res[0];
    unsigned gstar = res2[0];
    unsigned tid = blockIdx.x * 256 + threadIdx.x;
    unsigned nth = gridDim.x * 256;
    for (unsigned i0 = tid; i0 < nc; i0 += 4 * nth) {
        float v[4];
        #pragma unroll
        for (int u = 0; u < 4; ++u) {
            unsigned j = i0 + u * nth;
            v[u] = (j < nc) ? cval[j] : -1e30f;
        }
        #pragma unroll
        for (int u = 0; u < 4; ++u) {
            unsigned j = i0 + u * nth;
            if (j < nc) {
                unsigned g = (f2key(v[u]) - base) >> P2_SHIFT;
                if (g > P2_BINS - 1) g = P2_BINS - 1;
                if (g > gstar) {
                    out[cidx[j]] = fmaxf(v[u], 0.0f);    // definite winner
                } else if (g == gstar) {
                    unsigned p = atomicAdd(cnt2, 1u);
                    if (p < CAP2) { cval2[p] = v[u]; cidx2[p] = cidx[j]; }
                }
            }
        }
    }
}

// ---------------- C4: exact select in 4096-key range, ties, EMA ------------
__global__ __launch_bounds__(256) void final_kernel(
        const float* __restrict__ cval2, const unsigned* __restrict__ cidx2,
        const unsigned* __restrict__ cnt2,
        const unsigned* __restrict__ res, const unsigned* __restrict__ res2,
        float* __restrict__ out,
        const float* __restrict__ thr_in, float* __restrict__ thr_out) {
    __shared__ unsigned h[1 << P2_SHIFT];     // one bin per exact key
    __shared__ unsigned psum[256];
    __shared__ unsigned eqidx[EQCAP];
    __shared__ unsigned eqcnt;
    __shared__ unsigned sh_low, sh_need3;
    const int NB = 1 << P2_SHIFT;             // 4096
    int t = threadIdx.x;
    unsigned nc2   = min(*cnt2, CAP2);
    unsigned base3 = res[0] + (res2[0] << P2_SHIFT);
    unsigned need2 = res2[1];

    for (int i = t; i < NB; i += 256) h[i] = 0;
    if (t == 0) eqcnt = 0;
    __syncthreads();
    for (unsigned i = t; i < nc2; i += 256) {
        unsigned low = f2key(cval2[i]) - base3;
        if (low > (unsigned)(NB - 1)) low = NB - 1;
        atomicAdd(&h[low], 1u);
    }
    __syncthreads();

    const int GB = NB / 256;                  // 16 keys/thread, descending
    int hi = NB - 1 - t * GB;
    unsigned s = 0;
    for (int j = 0; j < GB; ++j) s += h[hi - j];
    psum[t] = s;
    __syncthreads();
    for (int off = 1; off < 256; off <<= 1) {
        unsigned o = (t >= off) ? psum[t - off] : 0u;
        __syncthreads();
        psum[t] += o;
        __syncthreads();
    }
    unsigned cum = psum[t] - s;
    for (int j = 0; j < GB; ++j) {
        unsigned c = h[hi - j];
        if (cum < need2 && cum + c >= need2) {
            sh_low = (unsigned)(hi - j);
            sh_need3 = need2 - cum;           // ties to accept at kth key
        }
        cum += c;
    }
    __syncthreads();
    unsigned kth_key = base3 + sh_low;
    unsigned need3   = sh_need3;

    for (unsigned i = t; i < nc2; i += 256) {
        float x = cval2[i];
        unsigned key = f2key(x);
        if (key > kth_key) {
            out[cidx2[i]] = fmaxf(x, 0.0f);
        } else if (key == kth_key) {
            unsigned p = atomicAdd(&eqcnt, 1u);
            if (p < EQCAP) eqidx[p] = cidx2[i];
        }
    }
    __syncthreads();

    // tie-break: lax.top_k picks lowest flat indices first
    unsigned ne = min(eqcnt, (unsigned)EQCAP);
    float vv = key2f(kth_key);
    for (unsigned e = t; e < ne; e += 256) {
        unsigned my = eqidx[e];
        unsigned rank = 0;
        for (unsigned f = 0; f < ne; ++f) rank += (eqidx[f] < my) ? 1u : 0u;
        if (rank < need3) out[my] = fmaxf(vv, 0.0f);
    }

    if (t == 0) {
        float mink = fmaxf(vv, 0.0f);         // relu(k-th largest)
        thr_out[0] = (1.0f - EMA_RATE) * thr_in[0] + EMA_RATE * mink;
    }
}

// ---------------- launch ----------------
extern "C" void kernel_launch(void* const* d_in, const int* in_sizes, int n_in,
                              void* d_out, int out_size, void* d_ws, size_t ws_size,
                              hipStream_t stream) {
    const float* feat   = (const float*)d_in[0];
    const float* thr_in = (const float*)d_in[1];
    float* out = (float*)d_out;
    int N    = in_sizes[0];      // 25165824
    int nvec = N / 4;

    // ---- workspace layout ----
    uint8_t* w = (uint8_t*)d_ws;
    unsigned* shist = (unsigned*)w;                        // 64 KB
    unsigned* ghist = (unsigned*)(w + (64 << 10));         // 16 KB
    unsigned* ctr   = (unsigned*)(w + (80 << 10));         // counters/res block
    unsigned* gcnt  = ctr + 0;
    unsigned* cnt2  = ctr + 1;
    unsigned* res   = ctr + 4;    // res[0] = base key
    unsigned* res2  = ctr + 8;    // res2[0] = g*, res2[1] = need2

    size_t cand_off = (size_t)1 << 20;
    size_t avail    = (ws_size > cand_off + (CAP2 * 8 + 4096))
                        ? (ws_size - cand_off - CAP2 * 8 - 4096) / 8 : 0;
    unsigned cap = (unsigned)((avail < (size_t)(4u << 20)) ? avail : (size_t)(4u << 20));
    float*    cval  = (float*)(w + cand_off);
    unsigned* cidx  = (unsigned*)(w + cand_off + (size_t)cap * 4);
    float*    cval2 = (float*)(w + cand_off + (size_t)cap * 8);
    unsigned* cidx2 = (unsigned*)(w + cand_off + (size_t)cap * 8 + CAP2 * 4);

    // zero hists + counters; zero the whole output (fill runs ~6.9 TB/s)
    hipMemsetAsync(d_ws, 0, (80 << 10) + 64, stream);
    hipMemsetAsync(d_out, 0, (size_t)N * 4, stream);

    sample_hist_kernel<<<128, 256, 0, stream>>>((const float4*)feat, shist);
    sample_scan_kernel<<<1,  1024, 0, stream>>>(shist, res);
    main_pass_kernel  <<<MP_BLOCKS, 256, 0, stream>>>((const float4*)feat, res,
                                                      cval, cidx, gcnt, cap, nvec);
    cand_hist_kernel  <<<128, 256, 0, stream>>>(cval, gcnt, res, ghist, cap);
    find_g_kernel     <<<1,  1024, 0, stream>>>(ghist, res2);
    scatter_kernel    <<<128, 256, 0, stream>>>(cval, cidx, gcnt, res, res2,
                                                cval2, cidx2, cnt2, cap, out);
    final_kernel      <<<1,   256, 0, stream>>>(cval2, cidx2, cnt2, res, res2,
                                                out, thr_in, out + N);
}